// Round 11
// baseline (181.676 us; speedup 1.0000x reference)
//
#include <hip/hip_runtime.h>

#define NF   16
#define C    8
#define NB   4
#define NPIX (512*512)

// plane-major sums: grid (CH, NF, NB) = 1024 blocks (under the ~100 WG/us
// launch-rate cap that bound R9's 4096-block variant). Each block streams one
// contiguous 64KB plane span + 64KB label span.
#define CH      16
#define CPX     (NPIX / CH)          // 16384 px per chunk
#define SITERS  (CPX / (256 * 4))    // 16 iterations, 4 px per thread each

// dist: DG blocks per batch; in-block means reduction from tiny PSUM (L2).
#define DG      256
#define DCHUNK  (NPIX / DG)          // 1024 px per block

// ws float layout (plain stores only; no global atomics anywhere):
//   PSUM: [b][f][ch][8]   4*16*16*8 = 8192 floats
//   PCNT: [b][ch][8]      4*16*8    = 512
//   POUT: [b][DG]                     1024
#define WS_PSUM 0
#define WS_PCNT (NB * NF * CH * 8)
#define WS_POUT (WS_PCNT + NB * CH * 8)

// LDS slot-accumulate: s_acc[tid*8 + lab] += p via ds_add_f32 (atomicAdd on
// shared, result unused -> no-return fast path). Each thread owns its 8-slot
// row -> no races; ~2 lanes/bank with random labels (2-way = free, m136).
// Replaces ~96 VALU masked-FMA ops per 4px with 4 LDS ops + addressing, and
// cuts VGPR so the 16-iteration load stream can pipeline deeply.
__global__ __launch_bounds__(256) void sums_kernel(const float* __restrict__ pred,
                                                   const int* __restrict__ tgt,
                                                   float* __restrict__ ws) {
    __shared__ float s_acc[256 * 8];     // 8 KB, per-thread class slots
    __shared__ float s_cnt[32];
    const int t    = threadIdx.x;
    const int lane = t & 63;
    const int wave = t >> 6;
    const int ch   = blockIdx.x;
    const int f    = blockIdx.y;
    const int b    = blockIdx.z;

    const float* pf = pred + ((size_t)b * NF + f) * NPIX + ch * CPX;
    const int*   tg = tgt  + (size_t)b * NPIX + ch * CPX;

#pragma unroll
    for (int c = 0; c < 8; ++c) s_acc[t * 8 + c] = 0.0f;

    float cnt[8];
#pragma unroll
    for (int c = 0; c < 8; ++c) cnt[c] = 0.0f;

#pragma unroll 4
    for (int it = 0; it < SITERS; ++it) {
        const int px = it * 1024 + t * 4;
        int4   lab = *(const int4*)(tg + px);
        float4 p   = *(const float4*)(pf + px);
        atomicAdd(&s_acc[t * 8 + lab.x], p.x);
        atomicAdd(&s_acc[t * 8 + lab.y], p.y);
        atomicAdd(&s_acc[t * 8 + lab.z], p.z);
        atomicAdd(&s_acc[t * 8 + lab.w], p.w);
        if (f == 0) {   // block-uniform branch: count pass only on f==0 blocks
#pragma unroll
            for (int c = 0; c < 8; ++c)
                cnt[c] += ((lab.x == c) ? 1.0f : 0.0f) + ((lab.y == c) ? 1.0f : 0.0f)
                        + ((lab.z == c) ? 1.0f : 0.0f) + ((lab.w == c) ? 1.0f : 0.0f);
        }
    }
    __syncthreads();

    // tree-reduce the 256 rows of 8 floats down to row 0
    for (int s = 128; s > 0; s >>= 1) {
        if (t < s) {
#pragma unroll
            for (int c = 0; c < 8; ++c)
                s_acc[t * 8 + c] += s_acc[(t + s) * 8 + c];
        }
        __syncthreads();
    }
    if (t < 8)
        ws[WS_PSUM + (((size_t)b * NF + f) * CH + ch) * 8 + t] = s_acc[t];

    if (f == 0) {
#pragma unroll
        for (int off = 32; off > 0; off >>= 1)
#pragma unroll
            for (int c = 0; c < 8; ++c)
                cnt[c] += __shfl_xor(cnt[c], off);
        if (lane == 0)
#pragma unroll
            for (int c = 0; c < 8; ++c) s_cnt[wave * 8 + c] = cnt[c];
        __syncthreads();
        if (t < 8)
            ws[WS_PCNT + (b * CH + ch) * 8 + t] =
                s_cnt[t] + s_cnt[8 + t] + s_cnt[16 + t] + s_cnt[24 + t];
    }
}

// dist with in-block means reduction (PSUM/PCNT ~34KB/batch, L2-resident).
__global__ __launch_bounds__(256) void dist_kernel(const float* __restrict__ pred,
                                                   const int* __restrict__ tgt,
                                                   const float* __restrict__ ws,
                                                   float* __restrict__ pout) {
    __shared__ float sm_p[2][128];
    __shared__ float scnt_p[8][8];
    __shared__ float scnt[8];
    __shared__ float s_means[128];
    __shared__ float s_invs;
    __shared__ float s_red[4];
    const int tid = threadIdx.x;
    const int b   = blockIdx.y;

    // counts: t<64 -> c=t&7, grp=t>>3 sums CH/8=2 chunks
    if (tid < 64) {
        const int c = tid & 7, grp = tid >> 3;
        float s = 0.0f;
#pragma unroll
        for (int i = 0; i < 2; ++i)
            s += ws[WS_PCNT + (b * CH + grp * 2 + i) * 8 + c];
        scnt_p[grp][c] = s;
    }
    // sums: fc = t&127, half = t>>7 sums 8 chunks each
    {
        const int fc = tid & 127, half = tid >> 7;
        const int f = fc >> 3, c = fc & 7;
        float s = 0.0f;
#pragma unroll
        for (int i = 0; i < 8; ++i)
            s += ws[WS_PSUM + (((size_t)b * NF + f) * CH + half * 8 + i) * 8 + c];
        sm_p[half][fc] = s;
    }
    __syncthreads();
    if (tid < 8) {
        float s = 0.0f;
#pragma unroll
        for (int grp = 0; grp < 8; ++grp) s += scnt_p[grp][tid];
        scnt[tid] = s;
    }
    __syncthreads();
    if (tid < 128)
        s_means[tid] = (sm_p[0][tid] + sm_p[1][tid]) / scnt[tid & 7];
    if (tid == 0) {
        float iv = 0.0f;
#pragma unroll
        for (int c = 0; c < 8; ++c) iv += 1.0f / scnt[c];
        s_invs = iv;
    }
    __syncthreads();

    const float* predb = pred + (size_t)b * NF * NPIX;
    const int*   tgtb  = tgt  + (size_t)b * NPIX;

    const int base = blockIdx.x * DCHUNK + tid * 4;
    int4 lab = *(const int4*)(tgtb + base);
    float s0 = 0.f, s1 = 0.f, s2 = 0.f, s3 = 0.f;
#pragma unroll
    for (int f = 0; f < NF; ++f) {
        float4 p = *(const float4*)(predb + f * NPIX + base);
        float d0 = s_means[f * C + lab.x] - p.x;
        float d1 = s_means[f * C + lab.y] - p.y;
        float d2 = s_means[f * C + lab.z] - p.z;
        float d3 = s_means[f * C + lab.w] - p.w;
        s0 += d0 * d0; s1 += d1 * d1; s2 += d2 * d2; s3 += d3 * d3;
    }
    float t0 = fminf(fmaxf(sqrtf(s0) - 0.5f, 0.0f), 100000.0f);
    float t1 = fminf(fmaxf(sqrtf(s1) - 0.5f, 0.0f), 100000.0f);
    float t2 = fminf(fmaxf(sqrtf(s2) - 0.5f, 0.0f), 100000.0f);
    float t3 = fminf(fmaxf(sqrtf(s3) - 0.5f, 0.0f), 100000.0f);
    float acc = t0 * t0 + t1 * t1 + t2 * t2 + t3 * t3;

#pragma unroll
    for (int off = 32; off > 0; off >>= 1) acc += __shfl_down(acc, off);
    const int lane = tid & 63, wave = tid >> 6;
    if (lane == 0) s_red[wave] = acc;
    __syncthreads();
    if (tid == 0) {
        float tot = s_red[0] + s_red[1] + s_red[2] + s_red[3];
        pout[b * DG + blockIdx.x] = tot * s_invs * 0.125f;
    }
}

// One block, 512 threads: sum the 1024 dist partials, plain store to out.
__global__ void final_kernel(const float* __restrict__ pout, float* __restrict__ out) {
    __shared__ float sr[8];
    const int t = threadIdx.x;
    float v = pout[t] + pout[t + 512];
#pragma unroll
    for (int off = 32; off > 0; off >>= 1) v += __shfl_xor(v, off);
    if ((t & 63) == 0) sr[t >> 6] = v;
    __syncthreads();
    if (t == 0) {
        float s = 0.0f;
#pragma unroll
        for (int i = 0; i < 8; ++i) s += sr[i];
        out[0] = s;
    }
}

extern "C" void kernel_launch(void* const* d_in, const int* in_sizes, int n_in,
                              void* d_out, int out_size, void* d_ws, size_t ws_size,
                              hipStream_t stream) {
    const float* pred = (const float*)d_in[0];
    const int*   tgt  = (const int*)d_in[1];
    float* out = (float*)d_out;
    float* ws  = (float*)d_ws;

    sums_kernel<<<dim3(CH, NF, NB), dim3(256), 0, stream>>>(pred, tgt, ws);
    dist_kernel<<<dim3(DG, NB), dim3(256), 0, stream>>>(pred, tgt, ws, ws + WS_POUT);
    final_kernel<<<dim3(1), dim3(512), 0, stream>>>(ws + WS_POUT, out);
}

// Round 12
// 119.902 us; speedup vs baseline: 1.5152x; 1.5152x over previous
//
#include <hip/hip_runtime.h>

#define NF   16
#define C    8
#define NB   4
#define NPIX (512*512)

// plane-major sums: grid (CH, NF, NB) = 512 blocks (2/CU, launch-light).
// Each block streams one contiguous 128KB plane span + label span with an
// explicit 2-deep rotating-register prefetch (named regs, no arrays).
#define CH      8
#define CPX     (NPIX / CH)          // 32768 px per chunk
#define PXI     2048                 // px per block-iteration (256 thr * 8)
#define NIT     (CPX / PXI)          // 16 iterations

// dist: DG blocks per batch; in-block means reduction from tiny PSUM (L2).
#define DG      256
#define DCHUNK  (NPIX / DG)          // 1024 px per block

// ws float layout (plain stores only; no atomics anywhere):
//   PSUM: [b][f][ch][8]   4*16*8*8 = 4096 floats
//   PCNT: [b][ch][8]      4*8*8    = 256
//   POUT: [b][DG]                    1024
#define WS_PSUM 0
#define WS_PCNT (NB * NF * CH * 8)
#define WS_POUT (WS_PCNT + NB * CH * 8)

__device__ __forceinline__ void acc4(const int4 lab, const float4 p, float acc[8]) {
#pragma unroll
    for (int c = 0; c < 8; ++c)
        acc[c] += ((lab.x == c) ? p.x : 0.0f) + ((lab.y == c) ? p.y : 0.0f)
                + ((lab.z == c) ? p.z : 0.0f) + ((lab.w == c) ? p.w : 0.0f);
}
__device__ __forceinline__ void cnt4(const int4 lab, float cnt[8]) {
#pragma unroll
    for (int c = 0; c < 8; ++c)
        cnt[c] += ((lab.x == c) ? 1.0f : 0.0f) + ((lab.y == c) ? 1.0f : 0.0f)
                + ((lab.z == c) ? 1.0f : 0.0f) + ((lab.w == c) ? 1.0f : 0.0f);
}

__global__ __launch_bounds__(256) void sums_kernel(const float* __restrict__ pred,
                                                   const int* __restrict__ tgt,
                                                   float* __restrict__ ws) {
    const int t    = threadIdx.x;
    const int lane = t & 63;
    const int wave = t >> 6;
    const int ch   = blockIdx.x;
    const int f    = blockIdx.y;
    const int b    = blockIdx.z;

    const float* pf = pred + ((size_t)b * NF + f) * NPIX + ch * CPX;
    const int*   tg = tgt  + (size_t)b * NPIX + ch * CPX;

    float acc[8], cnt[8];
#pragma unroll
    for (int c = 0; c < 8; ++c) { acc[c] = 0.0f; cnt[c] = 0.0f; }

    // rotating-register 2-deep pipeline: 4 loads in flight for the current
    // iteration + 4 issued for the next before any compute touches them.
    const int o = t * 8;
    int4   lA = *(const int4*)(tg + o);
    float4 vA = *(const float4*)(pf + o);
    int4   lB = *(const int4*)(tg + o + 4);
    float4 vB = *(const float4*)(pf + o + 4);

#pragma unroll 1
    for (int it = 0; it < NIT - 1; ++it) {
        const int n = (it + 1) * PXI + o;
        int4   lA1 = *(const int4*)(tg + n);
        float4 vA1 = *(const float4*)(pf + n);
        int4   lB1 = *(const int4*)(tg + n + 4);
        float4 vB1 = *(const float4*)(pf + n + 4);
        acc4(lA, vA, acc); acc4(lB, vB, acc);
        if (f == 0) { cnt4(lA, cnt); cnt4(lB, cnt); }
        lA = lA1; vA = vA1; lB = lB1; vB = vB1;
    }
    acc4(lA, vA, acc); acc4(lB, vB, acc);
    if (f == 0) { cnt4(lA, cnt); cnt4(lB, cnt); }

    // wave butterfly, then cross-wave via LDS
#pragma unroll
    for (int off = 32; off > 0; off >>= 1)
#pragma unroll
        for (int c = 0; c < 8; ++c)
            acc[c] += __shfl_xor(acc[c], off);
    if (f == 0) {
#pragma unroll
        for (int off = 32; off > 0; off >>= 1)
#pragma unroll
            for (int c = 0; c < 8; ++c)
                cnt[c] += __shfl_xor(cnt[c], off);
    }

    __shared__ float sred[4][8];
    __shared__ float scred[4][8];
    if (lane == 0) {
#pragma unroll
        for (int c = 0; c < 8; ++c) sred[wave][c] = acc[c];
        if (f == 0)
#pragma unroll
            for (int c = 0; c < 8; ++c) scred[wave][c] = cnt[c];
    }
    __syncthreads();
    if (t < 8)
        ws[WS_PSUM + (((size_t)b * NF + f) * CH + ch) * 8 + t] =
            sred[0][t] + sred[1][t] + sred[2][t] + sred[3][t];
    if (f == 0 && t >= 8 && t < 16) {
        const int c = t - 8;
        ws[WS_PCNT + (b * CH + ch) * 8 + c] =
            scred[0][c] + scred[1][c] + scred[2][c] + scred[3][c];
    }
}

// dist with in-block means reduction; 17 macro-named hoisted loads per thread.
__global__ __launch_bounds__(256) void dist_kernel(const float* __restrict__ pred,
                                                   const int* __restrict__ tgt,
                                                   const float* __restrict__ ws,
                                                   float* __restrict__ pout) {
    __shared__ float sm_p[2][128];
    __shared__ float scnt_p[8][8];
    __shared__ float scnt[8];
    __shared__ float s_means[128];
    __shared__ float s_invs;
    __shared__ float s_red[4];
    const int tid = threadIdx.x;
    const int b   = blockIdx.y;

    if (tid < 64) {
        const int c = tid & 7, grp = tid >> 3;
        scnt_p[grp][c] = ws[WS_PCNT + (b * CH + grp) * 8 + c];
    }
    {
        const int fc = tid & 127, half = tid >> 7;
        const int f = fc >> 3, c = fc & 7;
        float s = 0.0f;
#pragma unroll
        for (int i = 0; i < 4; ++i)
            s += ws[WS_PSUM + (((size_t)b * NF + f) * CH + half * 4 + i) * 8 + c];
        sm_p[half][fc] = s;
    }
    __syncthreads();
    if (tid < 8) {
        float s = 0.0f;
#pragma unroll
        for (int grp = 0; grp < 8; ++grp) s += scnt_p[grp][tid];
        scnt[tid] = s;
    }
    __syncthreads();
    if (tid < 128)
        s_means[tid] = (sm_p[0][tid] + sm_p[1][tid]) / scnt[tid & 7];
    if (tid == 0) {
        float iv = 0.0f;
#pragma unroll
        for (int c = 0; c < 8; ++c) iv += 1.0f / scnt[c];
        s_invs = iv;
    }
    __syncthreads();

    const float* predb = pred + (size_t)b * NF * NPIX;
    const int*   tgtb  = tgt  + (size_t)b * NPIX;

    const int base = blockIdx.x * DCHUNK + tid * 4;
    int4 lab = *(const int4*)(tgtb + base);
#define LP(i) float4 p##i = *(const float4*)(predb + (i) * NPIX + base);
    LP(0) LP(1) LP(2) LP(3) LP(4) LP(5) LP(6) LP(7)
    LP(8) LP(9) LP(10) LP(11) LP(12) LP(13) LP(14) LP(15)
#undef LP
    float s0 = 0.f, s1 = 0.f, s2 = 0.f, s3 = 0.f;
#define AC(i) { \
    float d0 = s_means[(i) * C + lab.x] - p##i.x; \
    float d1 = s_means[(i) * C + lab.y] - p##i.y; \
    float d2 = s_means[(i) * C + lab.z] - p##i.z; \
    float d3 = s_means[(i) * C + lab.w] - p##i.w; \
    s0 += d0 * d0; s1 += d1 * d1; s2 += d2 * d2; s3 += d3 * d3; }
    AC(0) AC(1) AC(2) AC(3) AC(4) AC(5) AC(6) AC(7)
    AC(8) AC(9) AC(10) AC(11) AC(12) AC(13) AC(14) AC(15)
#undef AC
    float t0 = fminf(fmaxf(sqrtf(s0) - 0.5f, 0.0f), 100000.0f);
    float t1 = fminf(fmaxf(sqrtf(s1) - 0.5f, 0.0f), 100000.0f);
    float t2 = fminf(fmaxf(sqrtf(s2) - 0.5f, 0.0f), 100000.0f);
    float t3 = fminf(fmaxf(sqrtf(s3) - 0.5f, 0.0f), 100000.0f);
    float acc = t0 * t0 + t1 * t1 + t2 * t2 + t3 * t3;

#pragma unroll
    for (int off = 32; off > 0; off >>= 1) acc += __shfl_down(acc, off);
    const int lane = tid & 63, wave = tid >> 6;
    if (lane == 0) s_red[wave] = acc;
    __syncthreads();
    if (tid == 0) {
        float tot = s_red[0] + s_red[1] + s_red[2] + s_red[3];
        pout[b * DG + blockIdx.x] = tot * s_invs * 0.125f;
    }
}

// One block, 512 threads: sum the 1024 dist partials, plain store to out.
__global__ void final_kernel(const float* __restrict__ pout, float* __restrict__ out) {
    __shared__ float sr[8];
    const int t = threadIdx.x;
    float v = pout[t] + pout[t + 512];
#pragma unroll
    for (int off = 32; off > 0; off >>= 1) v += __shfl_xor(v, off);
    if ((t & 63) == 0) sr[t >> 6] = v;
    __syncthreads();
    if (t == 0) {
        float s = 0.0f;
#pragma unroll
        for (int i = 0; i < 8; ++i) s += sr[i];
        out[0] = s;
    }
}

extern "C" void kernel_launch(void* const* d_in, const int* in_sizes, int n_in,
                              void* d_out, int out_size, void* d_ws, size_t ws_size,
                              hipStream_t stream) {
    const float* pred = (const float*)d_in[0];
    const int*   tgt  = (const int*)d_in[1];
    float* out = (float*)d_out;
    float* ws  = (float*)d_ws;

    sums_kernel<<<dim3(CH, NF, NB), dim3(256), 0, stream>>>(pred, tgt, ws);
    dist_kernel<<<dim3(DG, NB), dim3(256), 0, stream>>>(pred, tgt, ws, ws + WS_POUT);
    final_kernel<<<dim3(1), dim3(512), 0, stream>>>(ws + WS_POUT, out);
}